// Round 13
// baseline (177.260 us; speedup 1.0000x reference)
//
#include <hip/hip_runtime.h>
#include <hip/hip_bf16.h>

#define B_ 2
#define T_ 2048
#define C_ 1024
#define H_ 16
#define HD_ 64
#define O_ 1152   // C + 2*HD

#define NX  (B_ * T_ * C_)      // 4194304
#define NW1 (O_ * C_)           // 1179648
#define NW2 (C_ * C_)           // 1048576

// softmax runs in exp2 domain: Q pre-scale = (1/8) * log2(e)
#define QSCALE 0.1803368801111244f

typedef __attribute__((ext_vector_type(8))) short bf16x8;
typedef __attribute__((ext_vector_type(4))) float f32x4;
typedef __attribute__((ext_vector_type(16))) float f32x16;
typedef __attribute__((ext_vector_type(4))) unsigned u32x4;
typedef __attribute__((ext_vector_type(2))) unsigned u32x2;

__device__ inline short f2bf(float f) {
    union { float f; unsigned u; } v; v.f = f;
    unsigned r = v.u + 0x7FFFu + ((v.u >> 16) & 1u);
    return (short)(r >> 16);
}
__device__ inline float bf2f(short s) {
    union { unsigned u; float f; } v; v.u = ((unsigned)(unsigned short)s) << 16;
    return v.f;
}
// native 2^x (v_exp_f32)
__device__ inline float exp2fast(float x) { return __builtin_amdgcn_exp2f(x); }
// packed bf16(lo) | bf16(hi)<<16, RNE
__device__ inline unsigned cvtpk(float lo, float hi) {
    unsigned r;
    asm("v_cvt_pk_bf16_f32 %0, %1, %2" : "=v"(r) : "v"(lo), "v"(hi));
    return r;
}
// permlane32_swap via builtin (hazard-safe: compiler inserts the required
// VALU->permlane wait states; raw inline asm did not - round 10 failure).
__device__ inline u32x2 pswap(unsigned a, unsigned b) {
    return __builtin_amdgcn_permlane32_swap(a, b, false, false);
}
// cross-half (lane^32) max/add, direction-agnostic
__device__ inline float xmax32(float x) {
    u32x2 r = pswap(__float_as_uint(x), __float_as_uint(x));
    return fmaxf(__uint_as_float(r[0]), __uint_as_float(r[1]));
}
__device__ inline float xadd32(float x) {
    u32x2 r = pswap(__float_as_uint(x), __float_as_uint(x));
    return __uint_as_float(r[0]) + __uint_as_float(r[1]);
}

// -------- f32 -> bf16 pre-conversion of x, Wqkv, Wproj (one launch) --------
__global__ __launch_bounds__(256) void cvt_bf16(const float* __restrict__ x,
        const float* __restrict__ w1, const float* __restrict__ w2,
        short* __restrict__ xb, short* __restrict__ w1b, short* __restrict__ w2b) {
    size_t i = ((size_t)blockIdx.x * 256 + threadIdx.x) * 8;
    const float* src; short* dst; size_t off;
    if (i < (size_t)NX)              { src = x;  dst = xb;  off = i; }
    else if (i < (size_t)NX + NW1)   { src = w1; dst = w1b; off = i - NX; }
    else                             { src = w2; dst = w2b; off = i - NX - NW1; }
    f32x4 a = *(const f32x4*)(src + off);
    f32x4 b = *(const f32x4*)(src + off + 4);
    bf16x8 r;
    r[0] = f2bf(a[0]); r[1] = f2bf(a[1]); r[2] = f2bf(a[2]); r[3] = f2bf(a[3]);
    r[4] = f2bf(b[0]); r[5] = f2bf(b[1]); r[6] = f2bf(b[2]); r[7] = f2bf(b[3]);
    *(bf16x8*)(dst + off) = r;
}

// C(M,N) = A(M,K) * B(N,K)^T, bf16 inputs, fp32 accum.
// v6: 1-wave blocks, 64x64 tile, PLUS depth-2 software pipeline: 4-buffer
// ring, unroll-4 (K/32 = 32 steps = 8 iters). Loads for step s+2/s+3 fly
// under the MFMAs of steps s/s+1 (~256 cyc of MFMA covers ~200-300 cyc L2
// latency that depth-1 could not).
template <bool OUT_BF16>
__global__ __launch_bounds__(64) void gemm_bt(const short* __restrict__ A,
                                              const short* __restrict__ Bm,
                                              void* __restrict__ Cv,
                                              int M, int N, int K) {
    int ntn = N >> 6;
    int nwg = (M >> 6) * ntn;
    int cpx = nwg >> 3;                         // grids are %8 == 0
    int bid = (int)blockIdx.x;
    int swz = (bid % 8) * cpx + bid / 8;        // bijective XCD swizzle
    int m0 = (swz / ntn) << 6;
    int n0 = (swz % ntn) << 6;
    int l = threadIdx.x;
    int c = l & 15, g = l >> 4;
    int nstep = K >> 5;                          // 32 for K=1024

    f32x4 acc[4][4] = {};
    const short* Ap[4];
    const short* Bp[4];
    #pragma unroll
    for (int i = 0; i < 4; i++)
        Ap[i] = A + (size_t)(m0 + i * 16 + c) * K + g * 8;
    #pragma unroll
    for (int j = 0; j < 4; j++)
        Bp[j] = Bm + (size_t)(n0 + j * 16 + c) * K + g * 8;

    bf16x8 A0[4], B0[4], A1[4], B1[4], A2[4], B2[4], A3[4], B3[4];
    auto LD = [&](bf16x8 (&Aq)[4], bf16x8 (&Bq)[4], int st) {
        int k = (st < nstep ? st : nstep - 1) << 5;
        #pragma unroll
        for (int i = 0; i < 4; i++) {
            Aq[i] = *(const bf16x8*)(Ap[i] + k);
            Bq[i] = *(const bf16x8*)(Bp[i] + k);
        }
    };
    auto MM = [&](bf16x8 (&Aq)[4], bf16x8 (&Bq)[4]) {
        #pragma unroll
        for (int i = 0; i < 4; i++)
            #pragma unroll
            for (int j = 0; j < 4; j++)
                acc[i][j] = __builtin_amdgcn_mfma_f32_16x16x32_bf16(Aq[i], Bq[j], acc[i][j], 0, 0, 0);
    };

    LD(A0, B0, 0);
    LD(A1, B1, 1);
    for (int s = 0; s < nstep; s += 4) {
        LD(A2, B2, s + 2); MM(A0, B0);
        LD(A3, B3, s + 3); MM(A1, B1);
        LD(A0, B0, s + 4); MM(A2, B2);
        LD(A1, B1, s + 5); MM(A3, B3);
    }

    #pragma unroll
    for (int i = 0; i < 4; i++)
        #pragma unroll
        for (int j = 0; j < 4; j++)
            #pragma unroll
            for (int r = 0; r < 4; r++) {
                int rr = m0 + i * 16 + g * 4 + r;   // C/D row = (l>>4)*4 + reg
                int cc = n0 + j * 16 + c;           // C/D col = l&15
                if (OUT_BF16)
                    ((short*)Cv)[(size_t)rr * N + cc] = f2bf(acc[i][j][r]);
                else
                    ((float*)Cv)[(size_t)rr * N + cc] = acc[i][j][r];
            }
}

// Causal depthwise conv1d (K=3) + bias on bf16 qkv; splits -> Q (B,H,T,64,
// scaled QSCALE for exp2-domain softmax), K (B,T,64), V transposed (B,64,T).
__global__ __launch_bounds__(256) void conv_split(const short* __restrict__ qkv,
        const float* __restrict__ qw, const float* __restrict__ qb,
        const float* __restrict__ kw, const float* __restrict__ kbias,
        const float* __restrict__ vw, const float* __restrict__ vbias,
        short* __restrict__ Qs, short* __restrict__ Kb, short* __restrict__ Vt) {
    int idx = blockIdx.x * 256 + threadIdx.x;
    int ch = idx % O_;
    int bt = idx / O_;
    int t = bt % T_;
    int b = bt / T_;
    const short* p = qkv + (size_t)bt * O_ + ch;
    float x2 = bf2f(p[0]);
    float x1 = (t >= 1) ? bf2f(p[-O_]) : 0.f;
    float x0 = (t >= 2) ? bf2f(p[-2 * O_]) : 0.f;
    float w0, w1, w2, bias;
    if (ch < C_)             { w0 = qw[ch*3]; w1 = qw[ch*3+1]; w2 = qw[ch*3+2]; bias = qb[ch]; }
    else if (ch < C_ + HD_)  { int cc = ch - C_;       w0 = kw[cc*3]; w1 = kw[cc*3+1]; w2 = kw[cc*3+2]; bias = kbias[cc]; }
    else                     { int cc = ch - C_ - HD_; w0 = vw[cc*3]; w1 = vw[cc*3+1]; w2 = vw[cc*3+2]; bias = vbias[cc]; }
    float y = fmaf(x0, w0, fmaf(x1, w1, fmaf(x2, w2, bias)));
    if (ch < C_) {
        int h = ch >> 6, d = ch & 63;
        Qs[(((size_t)b * H_ + h) * T_ + t) * HD_ + d] = f2bf(y * QSCALE);
    } else if (ch < C_ + HD_) {
        Kb[((size_t)b * T_ + t) * HD_ + (ch - C_)] = f2bf(y);
    } else {
        Vt[((size_t)b * HD_ + (ch - C_ - HD_)) * T_ + t] = f2bf(y);
    }
}

// Flash-style causal MQA, v8: SPLIT-KV x2. Block = 4 waves = 2 q-tiles
// (p, 63-p), each q-tile's causal K-range halved across two waves (lo/hi).
// Per-wave serial tile count drops 32 -> <=16, and the grid grows to
// 1024 blocks x 4 waves = 4096 waves (4/SIMD) for latency hiding.
// Partials merged via exact flash combine through LDS + one barrier.
// Keeps: swapped QK^T (32x32x16), exp2 softmax, tree reductions, defer-max
// (T13), permlane32_swap (T12), K-tile register prefetch.
// C/D layout (m74-verified): col=lane&31, row=(reg&3)+8*(reg>>2)+4*(lane>>5).
__global__ __launch_bounds__(256) void attn_kernel(const short* __restrict__ Qs,
        const short* __restrict__ Kb, const short* __restrict__ Vt,
        short* __restrict__ Y) {
    __shared__ float OL[2][32 * 64];   // partner O (hi wave) per q-slot
    __shared__ float ML[2][64], LL[2][64];
    int bh = blockIdx.y;
    int b = bh >> 4;
    int h = bh & 15;
    int wid = threadIdx.x >> 6, l = threadIdx.x & 63;
    int ql = l & 31, hi = l >> 5;
    int p = (int)blockIdx.x;                   // 0..31, p=0 heaviest (first)
    int qs = wid >> 1;                         // q-slot within block
    int half = wid & 1;                        // 0 = lo K-half, 1 = hi K-half
    int qt = qs ? (63 - p) : p;
    int qbase = qt * 32;
    int qi = qbase + ql;

    // Q B-fragments (col=q=ql, d=hi*8+j)
    const short* Qp = Qs + ((size_t)bh * T_ + qi) * HD_ + hi * 8;
    bf16x8 qf[4];
    #pragma unroll
    for (int s = 0; s < 4; s++) qf[s] = *(const bf16x8*)(Qp + s * 16);

    f32x16 Oa0 = {}, Oa1 = {};                 // O^T, d-blocks [0,32) and [32,64)
    float mrow = -1e30f, lsum = 0.f;

    const short* Kbase = Kb + (size_t)b * T_ * HD_;
    const short* Vbase = Vt + (size_t)b * HD_ * T_;

    auto LDK = [&](int kt, bf16x8 (&dst)[8]) {
        #pragma unroll
        for (int s = 0; s < 4; s++) {
            dst[s]     = *(const bf16x8*)(Kbase + (size_t)(kt + ql) * HD_ + s * 16 + hi * 8);
            dst[4 + s] = *(const bf16x8*)(Kbase + (size_t)(kt + 32 + ql) * HD_ + s * 16 + hi * 8);
        }
    };

    int nt = (qt >> 1) + 1;                    // total K-tiles for this qt
    int nh0 = (nt + 1) >> 1;                   // lo half gets ceil(nt/2)
    int it0 = half ? nh0 : 0;
    int it1 = half ? nt : nh0;

    bf16x8 ka[8], kb2[8];
    if (it0 < it1) LDK(it0 * 64, ka);
    for (int it = it0; it < it1; it++) {
        int kt0 = it * 64;
        // ---- S^T from prefetched K ----
        f32x16 sv0 = {}, sv1 = {};
        #pragma unroll
        for (int s = 0; s < 4; s++)
            sv0 = __builtin_amdgcn_mfma_f32_32x32x16_bf16(ka[s], qf[s], sv0, 0, 0, 0);
        #pragma unroll
        for (int s = 0; s < 4; s++)
            sv1 = __builtin_amdgcn_mfma_f32_32x32x16_bf16(ka[4 + s], qf[s], sv1, 0, 0, 0);
        // ---- issue next tile's K loads (fly during softmax + PV) ----
        int itn = (it + 1 < it1) ? (it + 1) : it;
        LDK(itn * 64, kb2);
        // ---- causal mask (diagonal tile only; scale folded into Q) ----
        if (kt0 + 64 > qbase) {
            #pragma unroll
            for (int r = 0; r < 16; r++) {
                int kl = (r & 3) + 8 * (r >> 2) + 4 * hi;
                if (kt0 + kl > qi)      sv0[r] = -1e30f;
                if (kt0 + 32 + kl > qi) sv1[r] = -1e30f;
            }
        }
        // ---- row max: depth-5 tree + cross-half combine ----
        float t8[8];
        #pragma unroll
        for (int r = 0; r < 8; r++)
            t8[r] = fmaxf(fmaxf(sv0[r], sv0[r + 8]), fmaxf(sv1[r], sv1[r + 8]));
        float pmax = fmaxf(fmaxf(fmaxf(t8[0], t8[4]), fmaxf(t8[1], t8[5])),
                           fmaxf(fmaxf(t8[2], t8[6]), fmaxf(t8[3], t8[7])));
        pmax = xmax32(pmax);
        // ---- defer-max (T13): rescale only when max grew past THR=8 ----
        if (!__all(pmax <= mrow + 8.f)) {
            float nm = fmaxf(mrow, pmax);
            float alpha = exp2fast(mrow - nm);
            mrow = nm;
            lsum *= alpha;
            #pragma unroll
            for (int r = 0; r < 16; r++) { Oa0[r] *= alpha; Oa1[r] *= alpha; }
        }
        // ---- P = exp2(S - m); sum via depth-5 tree + cross-half add ----
        #pragma unroll
        for (int r = 0; r < 16; r++) sv0[r] = exp2fast(sv0[r] - mrow);
        #pragma unroll
        for (int r = 0; r < 16; r++) sv1[r] = exp2fast(sv1[r] - mrow);
        float s8[8];
        #pragma unroll
        for (int r = 0; r < 8; r++)
            s8[r] = (sv0[r] + sv0[r + 8]) + (sv1[r] + sv1[r + 8]);
        float psum = ((s8[0] + s8[4]) + (s8[1] + s8[5])) +
                     ((s8[2] + s8[6]) + (s8[3] + s8[7]));
        lsum += xadd32(psum);
        // ---- P redistribution: cvt_pk + permlane32_swap ----
        #pragma unroll
        for (int sub = 0; sub < 2; sub++) {
            #pragma unroll
            for (int hh = 0; hh < 2; hh++) {
                unsigned X0, X1, X2, X3;
                if (sub == 0) {
                    X0 = cvtpk(sv0[hh * 8 + 0], sv0[hh * 8 + 1]);
                    X1 = cvtpk(sv0[hh * 8 + 2], sv0[hh * 8 + 3]);
                    X2 = cvtpk(sv0[hh * 8 + 4], sv0[hh * 8 + 5]);
                    X3 = cvtpk(sv0[hh * 8 + 6], sv0[hh * 8 + 7]);
                } else {
                    X0 = cvtpk(sv1[hh * 8 + 0], sv1[hh * 8 + 1]);
                    X1 = cvtpk(sv1[hh * 8 + 2], sv1[hh * 8 + 3]);
                    X2 = cvtpk(sv1[hh * 8 + 4], sv1[hh * 8 + 5]);
                    X3 = cvtpk(sv1[hh * 8 + 6], sv1[hh * 8 + 7]);
                }
                u32x2 r02 = pswap(X0, X2);
                u32x2 r13 = pswap(X1, X3);
                union { u32x4 u; bf16x8 v; } pw;
                pw.u[0] = r02[0];   // k elems (hi*8 + 0,1)
                pw.u[1] = r13[0];   // k elems (hi*8 + 2,3)
                pw.u[2] = r02[1];   // k elems (hi*8 + 4,5)
                pw.u[3] = r13[1];   // k elems (hi*8 + 6,7)
                int koff = kt0 + sub * 32 + hh * 16 + hi * 8;
                bf16x8 va0 = *(const bf16x8*)(Vbase + (size_t)ql * T_ + koff);
                bf16x8 va1 = *(const bf16x8*)(Vbase + (size_t)(32 + ql) * T_ + koff);
                Oa0 = __builtin_amdgcn_mfma_f32_32x32x16_bf16(va0, pw.v, Oa0, 0, 0, 0);
                Oa1 = __builtin_amdgcn_mfma_f32_32x32x16_bf16(va1, pw.v, Oa1, 0, 0, 0);
            }
        }
        // ---- rotate prefetch buffer ----
        #pragma unroll
        for (int s = 0; s < 8; s++) ka[s] = kb2[s];
    }

    // ---- flash combine: hi wave publishes, lo wave merges & writes ----
    if (half) {
        #pragma unroll
        for (int r = 0; r < 16; r++) {
            OL[qs][r * 64 + l]        = Oa0[r];
            OL[qs][(16 + r) * 64 + l] = Oa1[r];
        }
        ML[qs][l] = mrow;
        LL[qs][l] = lsum;
    }
    __syncthreads();
    if (!half) {
        float m2 = ML[qs][l];
        float l2 = LL[qs][l];
        float mm = fmaxf(mrow, m2);
        float alo = exp2fast(mrow - mm);
        float ahi = exp2fast(m2 - mm);      // m2=-1e30 (empty hi) -> 0
        float inv = 1.f / (lsum * alo + l2 * ahi);
        size_t orow = ((size_t)b * T_ + qi) * C_ + h * HD_;
        #pragma unroll
        for (int r = 0; r < 16; r += 2) {
            float o0a = (Oa0[r]     * alo + OL[qs][r * 64 + l]          * ahi) * inv;
            float o0b = (Oa0[r + 1] * alo + OL[qs][(r + 1) * 64 + l]    * ahi) * inv;
            float o1a = (Oa1[r]     * alo + OL[qs][(16 + r) * 64 + l]   * ahi) * inv;
            float o1b = (Oa1[r + 1] * alo + OL[qs][(17 + r) * 64 + l]   * ahi) * inv;
            int d = (r & 3) + 8 * (r >> 2) + 4 * hi;   // (r,r+1)->(d,d+1)
            *(unsigned*)(Y + orow + d)      = cvtpk(o0a, o0b);
            *(unsigned*)(Y + orow + 32 + d) = cvtpk(o1a, o1b);
        }
    }
}

extern "C" void kernel_launch(void* const* d_in, const int* in_sizes, int n_in,
                              void* d_out, int out_size, void* d_ws, size_t ws_size,
                              hipStream_t stream) {
    const float* x     = (const float*)d_in[0];
    const float* Wqkv  = (const float*)d_in[1];
    const float* qw    = (const float*)d_in[2];
    const float* qb    = (const float*)d_in[3];
    const float* kw    = (const float*)d_in[4];
    const float* kbias = (const float*)d_in[5];
    const float* vw    = (const float*)d_in[6];
    const float* vbias = (const float*)d_in[7];
    const float* Wproj = (const float*)d_in[8];

    char* ws = (char*)d_ws;
    short* xb     = (short*)ws;                    //  8388608 B (reused as Ybf later)
    short* Wqkvb  = (short*)(ws + 8388608);        //  2359296 B
    short* Wprojb = (short*)(ws + 10747904);       //  2097152 B
    short* qkvb   = (short*)(ws + 12845056);       //  9437184 B
    short* Qsc    = (short*)(ws + 22282240);       //  8388608 B
    short* Kbf    = (short*)(ws + 30670848);       //   524288 B
    short* Vtr    = (short*)(ws + 31195136);       //   524288 B  (total 31.7 MB)
    short* Ybf    = xb;                            // x dead after gemm1

    const int M = B_ * T_;  // 4096

    // 0) f32 -> bf16: x, Wqkv, Wproj
    cvt_bf16<<<dim3(3136), 256, 0, stream>>>(x, Wqkv, Wproj, xb, Wqkvb, Wprojb);

    // 1) qkv = x @ Wqkv^T  (bf16 out)   grid 64*18 = 1152 (%8==0)
    gemm_bt<true><<<dim3((M / 64) * (O_ / 64)), 64, 0, stream>>>(
        xb, Wqkvb, qkvb, M, O_, C_);

    // 2) causal dwconv + split + scale + V-transpose
    conv_split<<<dim3((B_ * T_ * O_) / 256), 256, 0, stream>>>(
        qkvb, qw, qb, kw, kbias, vw, vbias, Qsc, Kbf, Vtr);

    // 3) causal MQA attention -> y (B,T,C) bf16   (split-KV x2)
    attn_kernel<<<dim3(32, B_ * H_), 256, 0, stream>>>(Qsc, Kbf, Vtr, Ybf);

    // 4) out = y @ Wproj^T -> f32 d_out   grid 64*16 = 1024 (%8==0)
    gemm_bt<false><<<dim3((M / 64) * (C_ / 64)), 64, 0, stream>>>(
        Ybf, Wprojb, (float*)d_out, M, C_, C_);
}

// Round 14
// 164.971 us; speedup vs baseline: 1.0745x; 1.0745x over previous
//
#include <hip/hip_runtime.h>
#include <hip/hip_bf16.h>

#define B_ 2
#define T_ 2048
#define C_ 1024
#define H_ 16
#define HD_ 64
#define O_ 1152   // C + 2*HD

#define NX  (B_ * T_ * C_)      // 4194304
#define NW1 (O_ * C_)           // 1179648
#define NW2 (C_ * C_)           // 1048576

// softmax runs in exp2 domain: Q pre-scale = (1/8) * log2(e)
#define QSCALE 0.1803368801111244f

typedef __attribute__((ext_vector_type(8))) short bf16x8;
typedef __attribute__((ext_vector_type(4))) float f32x4;
typedef __attribute__((ext_vector_type(16))) float f32x16;
typedef __attribute__((ext_vector_type(4))) unsigned u32x4;
typedef __attribute__((ext_vector_type(2))) unsigned u32x2;

__device__ inline short f2bf(float f) {
    union { float f; unsigned u; } v; v.f = f;
    unsigned r = v.u + 0x7FFFu + ((v.u >> 16) & 1u);
    return (short)(r >> 16);
}
__device__ inline float bf2f(short s) {
    union { unsigned u; float f; } v; v.u = ((unsigned)(unsigned short)s) << 16;
    return v.f;
}
// native 2^x (v_exp_f32)
__device__ inline float exp2fast(float x) { return __builtin_amdgcn_exp2f(x); }
// packed bf16(lo) | bf16(hi)<<16, RNE
__device__ inline unsigned cvtpk(float lo, float hi) {
    unsigned r;
    asm("v_cvt_pk_bf16_f32 %0, %1, %2" : "=v"(r) : "v"(lo), "v"(hi));
    return r;
}
// permlane32_swap via builtin (hazard-safe: compiler inserts the required
// VALU->permlane wait states; raw inline asm did not - round 10 failure).
__device__ inline u32x2 pswap(unsigned a, unsigned b) {
    return __builtin_amdgcn_permlane32_swap(a, b, false, false);
}
// cross-half (lane^32) max/add, direction-agnostic
__device__ inline float xmax32(float x) {
    u32x2 r = pswap(__float_as_uint(x), __float_as_uint(x));
    return fmaxf(__uint_as_float(r[0]), __uint_as_float(r[1]));
}
__device__ inline float xadd32(float x) {
    u32x2 r = pswap(__float_as_uint(x), __float_as_uint(x));
    return __uint_as_float(r[0]) + __uint_as_float(r[1]);
}

// -------- f32 -> bf16 pre-conversion of x, Wqkv, Wproj (one launch) --------
__global__ __launch_bounds__(256) void cvt_bf16(const float* __restrict__ x,
        const float* __restrict__ w1, const float* __restrict__ w2,
        short* __restrict__ xb, short* __restrict__ w1b, short* __restrict__ w2b) {
    size_t i = ((size_t)blockIdx.x * 256 + threadIdx.x) * 8;
    const float* src; short* dst; size_t off;
    if (i < (size_t)NX)              { src = x;  dst = xb;  off = i; }
    else if (i < (size_t)NX + NW1)   { src = w1; dst = w1b; off = i - NX; }
    else                             { src = w2; dst = w2b; off = i - NX - NW1; }
    f32x4 a = *(const f32x4*)(src + off);
    f32x4 b = *(const f32x4*)(src + off + 4);
    bf16x8 r;
    r[0] = f2bf(a[0]); r[1] = f2bf(a[1]); r[2] = f2bf(a[2]); r[3] = f2bf(a[3]);
    r[4] = f2bf(b[0]); r[5] = f2bf(b[1]); r[6] = f2bf(b[2]); r[7] = f2bf(b[3]);
    *(bf16x8*)(dst + off) = r;
}

// C(M,N) = A(M,K) * B(N,K)^T, bf16 inputs, fp32 accum.
// v7: 1-wave blocks, 128x64 tile (M x N) = 8x4 frags -> 32 MFMA (256 cyc)
// per 12 loads per k-step, depth-1 register prefetch (r12's measured-good
// shape). Rationale: GEMM is L2-miss-latency-bound with ~1 wave/SIMD; the
// only lever is more MFMA work per serial miss-chain -> halve the number of
// miss-chains per output byte vs 64x64.
template <bool OUT_BF16>
__global__ __launch_bounds__(64) void gemm_bt(const short* __restrict__ A,
                                              const short* __restrict__ Bm,
                                              void* __restrict__ Cv,
                                              int M, int N, int K) {
    int ntn = N >> 6;
    int nwg = (M >> 7) * ntn;
    int cpx = nwg >> 3;                         // grids are %8 == 0
    int bid = (int)blockIdx.x;
    int swz = (bid % 8) * cpx + bid / 8;        // bijective XCD swizzle
    int m0 = (swz / ntn) << 7;
    int n0 = (swz % ntn) << 6;
    int l = threadIdx.x;
    int c = l & 15, g = l >> 4;

    f32x4 acc[8][4] = {};
    const short* Ap[8];
    const short* Bp[4];
    #pragma unroll
    for (int i = 0; i < 8; i++)
        Ap[i] = A + (size_t)(m0 + i * 16 + c) * K + g * 8;
    #pragma unroll
    for (int j = 0; j < 4; j++)
        Bp[j] = Bm + (size_t)(n0 + j * 16 + c) * K + g * 8;

    bf16x8 a[8], b[4], a2[8], b2[4];
    #pragma unroll
    for (int i = 0; i < 8; i++) a[i] = *(const bf16x8*)Ap[i];
    #pragma unroll
    for (int j = 0; j < 4; j++) b[j] = *(const bf16x8*)Bp[j];

    for (int k0 = 0; k0 < K; k0 += 32) {
        int kn = (k0 + 32 < K) ? (k0 + 32) : k0;   // last iter: harmless reload
        #pragma unroll
        for (int i = 0; i < 8; i++) a2[i] = *(const bf16x8*)(Ap[i] + kn);
        #pragma unroll
        for (int j = 0; j < 4; j++) b2[j] = *(const bf16x8*)(Bp[j] + kn);
        #pragma unroll
        for (int i = 0; i < 8; i++)
            #pragma unroll
            for (int j = 0; j < 4; j++)
                acc[i][j] = __builtin_amdgcn_mfma_f32_16x16x32_bf16(a[i], b[j], acc[i][j], 0, 0, 0);
        #pragma unroll
        for (int i = 0; i < 8; i++) a[i] = a2[i];
        #pragma unroll
        for (int j = 0; j < 4; j++) b[j] = b2[j];
    }

    #pragma unroll
    for (int i = 0; i < 8; i++)
        #pragma unroll
        for (int j = 0; j < 4; j++)
            #pragma unroll
            for (int r = 0; r < 4; r++) {
                int rr = m0 + i * 16 + g * 4 + r;   // C/D row = (l>>4)*4 + reg
                int cc = n0 + j * 16 + c;           // C/D col = l&15
                if (OUT_BF16)
                    ((short*)Cv)[(size_t)rr * N + cc] = f2bf(acc[i][j][r]);
                else
                    ((float*)Cv)[(size_t)rr * N + cc] = acc[i][j][r];
            }
}

// Causal depthwise conv1d (K=3) + bias on bf16 qkv; splits -> Q (B,H,T,64,
// scaled QSCALE for exp2-domain softmax), K (B,T,64), V transposed (B,64,T).
__global__ __launch_bounds__(256) void conv_split(const short* __restrict__ qkv,
        const float* __restrict__ qw, const float* __restrict__ qb,
        const float* __restrict__ kw, const float* __restrict__ kbias,
        const float* __restrict__ vw, const float* __restrict__ vbias,
        short* __restrict__ Qs, short* __restrict__ Kb, short* __restrict__ Vt) {
    int idx = blockIdx.x * 256 + threadIdx.x;
    int ch = idx % O_;
    int bt = idx / O_;
    int t = bt % T_;
    int b = bt / T_;
    const short* p = qkv + (size_t)bt * O_ + ch;
    float x2 = bf2f(p[0]);
    float x1 = (t >= 1) ? bf2f(p[-O_]) : 0.f;
    float x0 = (t >= 2) ? bf2f(p[-2 * O_]) : 0.f;
    float w0, w1, w2, bias;
    if (ch < C_)             { w0 = qw[ch*3]; w1 = qw[ch*3+1]; w2 = qw[ch*3+2]; bias = qb[ch]; }
    else if (ch < C_ + HD_)  { int cc = ch - C_;       w0 = kw[cc*3]; w1 = kw[cc*3+1]; w2 = kw[cc*3+2]; bias = kbias[cc]; }
    else                     { int cc = ch - C_ - HD_; w0 = vw[cc*3]; w1 = vw[cc*3+1]; w2 = vw[cc*3+2]; bias = vbias[cc]; }
    float y = fmaf(x0, w0, fmaf(x1, w1, fmaf(x2, w2, bias)));
    if (ch < C_) {
        int h = ch >> 6, d = ch & 63;
        Qs[(((size_t)b * H_ + h) * T_ + t) * HD_ + d] = f2bf(y * QSCALE);
    } else if (ch < C_ + HD_) {
        Kb[((size_t)b * T_ + t) * HD_ + (ch - C_)] = f2bf(y);
    } else {
        Vt[((size_t)b * HD_ + (ch - C_ - HD_)) * T_ + t] = f2bf(y);
    }
}

// Flash-style causal MQA — EXACT round-12 kernel (best measured: 71.7 us).
// 4-wave sum-balanced blocks, swapped QK^T (32x32x16), exp2 softmax, tree
// reductions, defer-max (T13), permlane32_swap (T12), K-tile reg prefetch.
// C/D layout (m74-verified): col=lane&31, row=(reg&3)+8*(reg>>2)+4*(lane>>5).
__global__ __launch_bounds__(256) void attn_kernel(const short* __restrict__ Qs,
        const short* __restrict__ Kb, const short* __restrict__ Vt,
        short* __restrict__ Y) {
    int bh = blockIdx.y;
    int b = bh >> 4;
    int h = bh & 15;
    int wid = threadIdx.x >> 6, l = threadIdx.x & 63;
    int ql = l & 31, hi = l >> 5;
    int k2 = blockIdx.x;                       // 0..15
    int qt = (wid < 2) ? (2 * k2 + wid) : (63 - 2 * k2 - (wid & 1));
    int qbase = qt * 32;
    int qi = qbase + ql;

    // Q B-fragments, 4 contraction steps of 16 over HD=64 (col=q=ql, d=hi*8+j)
    const short* Qp = Qs + ((size_t)bh * T_ + qi) * HD_ + hi * 8;
    bf16x8 qf[4];
    #pragma unroll
    for (int s = 0; s < 4; s++) qf[s] = *(const bf16x8*)(Qp + s * 16);

    f32x16 Oa0 = {}, Oa1 = {};                 // O^T, d-blocks [0,32) and [32,64)
    float mrow = -1e30f, lsum = 0.f;

    const short* Kbase = Kb + (size_t)b * T_ * HD_;
    const short* Vbase = Vt + (size_t)b * HD_ * T_;

    auto LDK = [&](int kt, bf16x8 (&dst)[8]) {
        #pragma unroll
        for (int s = 0; s < 4; s++) {
            dst[s]     = *(const bf16x8*)(Kbase + (size_t)(kt + ql) * HD_ + s * 16 + hi * 8);
            dst[4 + s] = *(const bf16x8*)(Kbase + (size_t)(kt + 32 + ql) * HD_ + s * 16 + hi * 8);
        }
    };

    int nt = (qt >> 1) + 1;
    bf16x8 ka[8], kb2[8];
    LDK(0, ka);
    for (int it = 0; it < nt; it++) {
        int kt0 = it * 64;
        // ---- S^T from prefetched K ----
        f32x16 sv0 = {}, sv1 = {};
        #pragma unroll
        for (int s = 0; s < 4; s++)
            sv0 = __builtin_amdgcn_mfma_f32_32x32x16_bf16(ka[s], qf[s], sv0, 0, 0, 0);
        #pragma unroll
        for (int s = 0; s < 4; s++)
            sv1 = __builtin_amdgcn_mfma_f32_32x32x16_bf16(ka[4 + s], qf[s], sv1, 0, 0, 0);
        // ---- issue next tile's K loads (fly during softmax + PV) ----
        int itn = (it + 1 < nt) ? (it + 1) : it;
        LDK(itn * 64, kb2);
        // ---- causal mask (last tile only; scale folded into Q) ----
        if (kt0 + 64 > qbase) {
            #pragma unroll
            for (int r = 0; r < 16; r++) {
                int kl = (r & 3) + 8 * (r >> 2) + 4 * hi;
                if (kt0 + kl > qi)      sv0[r] = -1e30f;
                if (kt0 + 32 + kl > qi) sv1[r] = -1e30f;
            }
        }
        // ---- row max: depth-5 tree + cross-half combine ----
        float t8[8];
        #pragma unroll
        for (int r = 0; r < 8; r++)
            t8[r] = fmaxf(fmaxf(sv0[r], sv0[r + 8]), fmaxf(sv1[r], sv1[r + 8]));
        float pmax = fmaxf(fmaxf(fmaxf(t8[0], t8[4]), fmaxf(t8[1], t8[5])),
                           fmaxf(fmaxf(t8[2], t8[6]), fmaxf(t8[3], t8[7])));
        pmax = xmax32(pmax);
        // ---- defer-max (T13): rescale only when max grew past THR=8 ----
        if (!__all(pmax <= mrow + 8.f)) {
            float nm = fmaxf(mrow, pmax);
            float alpha = exp2fast(mrow - nm);
            mrow = nm;
            lsum *= alpha;
            #pragma unroll
            for (int r = 0; r < 16; r++) { Oa0[r] *= alpha; Oa1[r] *= alpha; }
        }
        // ---- P = exp2(S - m); sum via depth-5 tree + cross-half add ----
        #pragma unroll
        for (int r = 0; r < 16; r++) sv0[r] = exp2fast(sv0[r] - mrow);
        #pragma unroll
        for (int r = 0; r < 16; r++) sv1[r] = exp2fast(sv1[r] - mrow);
        float s8[8];
        #pragma unroll
        for (int r = 0; r < 8; r++)
            s8[r] = (sv0[r] + sv0[r + 8]) + (sv1[r] + sv1[r + 8]);
        float psum = ((s8[0] + s8[4]) + (s8[1] + s8[5])) +
                     ((s8[2] + s8[6]) + (s8[3] + s8[7]));
        lsum += xadd32(psum);
        // ---- P redistribution: cvt_pk + permlane32_swap ----
        #pragma unroll
        for (int sub = 0; sub < 2; sub++) {
            #pragma unroll
            for (int hh = 0; hh < 2; hh++) {
                unsigned X0, X1, X2, X3;
                if (sub == 0) {
                    X0 = cvtpk(sv0[hh * 8 + 0], sv0[hh * 8 + 1]);
                    X1 = cvtpk(sv0[hh * 8 + 2], sv0[hh * 8 + 3]);
                    X2 = cvtpk(sv0[hh * 8 + 4], sv0[hh * 8 + 5]);
                    X3 = cvtpk(sv0[hh * 8 + 6], sv0[hh * 8 + 7]);
                } else {
                    X0 = cvtpk(sv1[hh * 8 + 0], sv1[hh * 8 + 1]);
                    X1 = cvtpk(sv1[hh * 8 + 2], sv1[hh * 8 + 3]);
                    X2 = cvtpk(sv1[hh * 8 + 4], sv1[hh * 8 + 5]);
                    X3 = cvtpk(sv1[hh * 8 + 6], sv1[hh * 8 + 7]);
                }
                u32x2 r02 = pswap(X0, X2);
                u32x2 r13 = pswap(X1, X3);
                union { u32x4 u; bf16x8 v; } pw;
                pw.u[0] = r02[0];   // k elems (hi*8 + 0,1)
                pw.u[1] = r13[0];   // k elems (hi*8 + 2,3)
                pw.u[2] = r02[1];   // k elems (hi*8 + 4,5)
                pw.u[3] = r13[1];   // k elems (hi*8 + 6,7)
                int koff = kt0 + sub * 32 + hh * 16 + hi * 8;
                bf16x8 va0 = *(const bf16x8*)(Vbase + (size_t)ql * T_ + koff);
                bf16x8 va1 = *(const bf16x8*)(Vbase + (size_t)(32 + ql) * T_ + koff);
                Oa0 = __builtin_amdgcn_mfma_f32_32x32x16_bf16(va0, pw.v, Oa0, 0, 0, 0);
                Oa1 = __builtin_amdgcn_mfma_f32_32x32x16_bf16(va1, pw.v, Oa1, 0, 0, 0);
            }
        }
        // ---- rotate prefetch buffer ----
        #pragma unroll
        for (int s = 0; s < 8; s++) ka[s] = kb2[s];
    }
    // ---- epilogue: normalize, write one Y-row segment per lane ----
    float inv = 1.f / lsum;
    size_t orow = ((size_t)b * T_ + qi) * C_ + h * HD_;
    #pragma unroll
    for (int r = 0; r < 16; r += 2) {
        int d = (r & 3) + 8 * (r >> 2) + 4 * hi;       // r even -> d even; (r,r+1)->(d,d+1)
        *(unsigned*)(Y + orow + d)      = cvtpk(Oa0[r] * inv, Oa0[r + 1] * inv);
        *(unsigned*)(Y + orow + 32 + d) = cvtpk(Oa1[r] * inv, Oa1[r + 1] * inv);
    }
}

extern "C" void kernel_launch(void* const* d_in, const int* in_sizes, int n_in,
                              void* d_out, int out_size, void* d_ws, size_t ws_size,
                              hipStream_t stream) {
    const float* x     = (const float*)d_in[0];
    const float* Wqkv  = (const float*)d_in[1];
    const float* qw    = (const float*)d_in[2];
    const float* qb    = (const float*)d_in[3];
    const float* kw    = (const float*)d_in[4];
    const float* kbias = (const float*)d_in[5];
    const float* vw    = (const float*)d_in[6];
    const float* vbias = (const float*)d_in[7];
    const float* Wproj = (const float*)d_in[8];

    char* ws = (char*)d_ws;
    short* xb     = (short*)ws;                    //  8388608 B (reused as Ybf later)
    short* Wqkvb  = (short*)(ws + 8388608);        //  2359296 B
    short* Wprojb = (short*)(ws + 10747904);       //  2097152 B
    short* qkvb   = (short*)(ws + 12845056);       //  9437184 B
    short* Qsc    = (short*)(ws + 22282240);       //  8388608 B
    short* Kbf    = (short*)(ws + 30670848);       //   524288 B
    short* Vtr    = (short*)(ws + 31195136);       //   524288 B  (total 31.7 MB)
    short* Ybf    = xb;                            // x dead after gemm1

    const int M = B_ * T_;  // 4096

    // 0) f32 -> bf16: x, Wqkv, Wproj
    cvt_bf16<<<dim3(3136), 256, 0, stream>>>(x, Wqkv, Wproj, xb, Wqkvb, Wprojb);

    // 1) qkv = x @ Wqkv^T  (bf16 out)   grid 32*18 = 576 (%8==0)
    gemm_bt<true><<<dim3((M / 128) * (O_ / 64)), 64, 0, stream>>>(
        xb, Wqkvb, qkvb, M, O_, C_);

    // 2) causal dwconv + split + scale + V-transpose
    conv_split<<<dim3((B_ * T_ * O_) / 256), 256, 0, stream>>>(
        qkvb, qw, qb, kw, kbias, vw, vbias, Qsc, Kbf, Vtr);

    // 3) causal MQA attention -> y (B,T,C) bf16   (round-12 structure)
    attn_kernel<<<dim3(16, B_ * H_), 256, 0, stream>>>(Qsc, Kbf, Vtr, Ybf);

    // 4) out = y @ Wproj^T -> f32 d_out   grid 32*16 = 512 (%8==0)
    gemm_bt<false><<<dim3((M / 128) * (C_ / 64)), 64, 0, stream>>>(
        Ybf, Wprojb, (float*)d_out, M, C_, C_);
}

// Round 15
// 147.314 us; speedup vs baseline: 1.2033x; 1.1199x over previous
//
#include <hip/hip_runtime.h>
#include <hip/hip_bf16.h>

#define B_ 2
#define T_ 2048
#define C_ 1024
#define H_ 16
#define HD_ 64
#define O_ 1152   // C + 2*HD

#define NX  (B_ * T_ * C_)      // 4194304
#define NW1 (O_ * C_)           // 1179648
#define NW2 (C_ * C_)           // 1048576

// softmax runs in exp2 domain: Q pre-scale = (1/8) * log2(e)
#define QSCALE 0.1803368801111244f

typedef __attribute__((ext_vector_type(8))) short bf16x8;
typedef __attribute__((ext_vector_type(4))) float f32x4;
typedef __attribute__((ext_vector_type(16))) float f32x16;
typedef __attribute__((ext_vector_type(4))) unsigned u32x4;
typedef __attribute__((ext_vector_type(2))) unsigned u32x2;

__device__ inline short f2bf(float f) {
    union { float f; unsigned u; } v; v.f = f;
    unsigned r = v.u + 0x7FFFu + ((v.u >> 16) & 1u);
    return (short)(r >> 16);
}
__device__ inline float bf2f(short s) {
    union { unsigned u; float f; } v; v.u = ((unsigned)(unsigned short)s) << 16;
    return v.f;
}
// native 2^x (v_exp_f32)
__device__ inline float exp2fast(float x) { return __builtin_amdgcn_exp2f(x); }
// packed bf16(lo) | bf16(hi)<<16, RNE
__device__ inline unsigned cvtpk(float lo, float hi) {
    unsigned r;
    asm("v_cvt_pk_bf16_f32 %0, %1, %2" : "=v"(r) : "v"(lo), "v"(hi));
    return r;
}
// permlane32_swap via builtin (hazard-safe: compiler inserts the required
// VALU->permlane wait states; raw inline asm did not - round 10 failure).
__device__ inline u32x2 pswap(unsigned a, unsigned b) {
    return __builtin_amdgcn_permlane32_swap(a, b, false, false);
}
// cross-half (lane^32) max/add, direction-agnostic
__device__ inline float xmax32(float x) {
    u32x2 r = pswap(__float_as_uint(x), __float_as_uint(x));
    return fmaxf(__uint_as_float(r[0]), __uint_as_float(r[1]));
}
__device__ inline float xadd32(float x) {
    u32x2 r = pswap(__float_as_uint(x), __float_as_uint(x));
    return __uint_as_float(r[0]) + __uint_as_float(r[1]);
}

// async global -> LDS, 16 B per lane (wave-uniform LDS base + lane*16)
#define GLL16(gp, lp) __builtin_amdgcn_global_load_lds( \
    (const __attribute__((address_space(1))) unsigned int*)(gp), \
    (__attribute__((address_space(3))) unsigned int*)(lp), 16, 0, 0)

// -------- f32 -> bf16 pre-conversion of x, Wqkv, Wproj (one launch) --------
__global__ __launch_bounds__(256) void cvt_bf16(const float* __restrict__ x,
        const float* __restrict__ w1, const float* __restrict__ w2,
        short* __restrict__ xb, short* __restrict__ w1b, short* __restrict__ w2b) {
    size_t i = ((size_t)blockIdx.x * 256 + threadIdx.x) * 8;
    const float* src; short* dst; size_t off;
    if (i < (size_t)NX)              { src = x;  dst = xb;  off = i; }
    else if (i < (size_t)NX + NW1)   { src = w1; dst = w1b; off = i - NX; }
    else                             { src = w2; dst = w2b; off = i - NX - NW1; }
    f32x4 a = *(const f32x4*)(src + off);
    f32x4 b = *(const f32x4*)(src + off + 4);
    bf16x8 r;
    r[0] = f2bf(a[0]); r[1] = f2bf(a[1]); r[2] = f2bf(a[2]); r[3] = f2bf(a[3]);
    r[4] = f2bf(b[0]); r[5] = f2bf(b[1]); r[6] = f2bf(b[2]); r[7] = f2bf(b[3]);
    *(bf16x8*)(dst + off) = r;
}

// C(M,N) = A(M,K) * B(N,K)^T, bf16 inputs, fp32 accum.
// v8 (m97-structure port): 128x128 block tile, 4 waves (2x2), each wave
// 64x64 = 4x4 frags of 16x16x32. BK=32. A/B tiles staged to LDS via
// global_load_lds width=16 (block-cooperative DMA; MFMAs run from LDS, so
// per-wave k-steps no longer eat HBM/L2 latency -- the reg-only structure's
// 240 TF ceiling was exactly that latency exposure). 2 barriers per k-step.
// Linear LDS [128][32] (known ds_read bank aliasing; m97 ships with it).
template <bool OUT_BF16>
__global__ __launch_bounds__(256) void gemm_bt(const short* __restrict__ A,
                                               const short* __restrict__ Bm,
                                               void* __restrict__ Cv,
                                               int M, int N, int K) {
    __shared__ short lA[128 * 32];   // 8 KB
    __shared__ short lB[128 * 32];   // 8 KB
    int ntn = N >> 7;
    int nwg = (M >> 7) * ntn;
    int cpx = nwg >> 3;                         // grids are %8 == 0
    int bid = (int)blockIdx.x;
    int swz = (bid % 8) * cpx + bid / 8;        // bijective XCD swizzle
    int m0 = (swz / ntn) << 7;
    int n0 = (swz % ntn) << 7;
    int t = threadIdx.x;
    int wid = t >> 6, l = t & 63;
    int wr = wid >> 1, wc = wid & 1;
    int c = l & 15, g = l >> 4;

    // staging: thread t covers LDS bytes [t*16, t*16+16) = row t/4, k-chunk t%4
    // (16 B = 8 bf16; row = 64 B). Issue 0: rows 0..63; issue 1: rows 64..127.
    const short* gA0 = A + (size_t)(m0 + (t >> 2)) * K + (t & 3) * 8;
    const short* gA1 = gA0 + (size_t)64 * K;
    const short* gB0 = Bm + (size_t)(n0 + (t >> 2)) * K + (t & 3) * 8;
    const short* gB1 = gB0 + (size_t)64 * K;
    short* lAd0 = &lA[t * 8];
    short* lAd1 = &lA[64 * 32 + t * 8];
    short* lBd0 = &lB[t * 8];
    short* lBd1 = &lB[64 * 32 + t * 8];

    const short* lap = &lA[(wr * 64 + c) * 32 + g * 8];
    const short* lbp = &lB[(wc * 64 + c) * 32 + g * 8];

    f32x4 acc[4][4] = {};
    for (int k0 = 0; k0 < K; k0 += 32) {
        GLL16(gA0 + k0, lAd0);
        GLL16(gA1 + k0, lAd1);
        GLL16(gB0 + k0, lBd0);
        GLL16(gB1 + k0, lBd1);
        __syncthreads();                        // vmcnt drain + barrier
        bf16x8 a[4], b[4];
        #pragma unroll
        for (int i = 0; i < 4; i++) a[i] = *(const bf16x8*)(lap + i * 16 * 32);
        #pragma unroll
        for (int j = 0; j < 4; j++) b[j] = *(const bf16x8*)(lbp + j * 16 * 32);
        #pragma unroll
        for (int i = 0; i < 4; i++)
            #pragma unroll
            for (int j = 0; j < 4; j++)
                acc[i][j] = __builtin_amdgcn_mfma_f32_16x16x32_bf16(a[i], b[j], acc[i][j], 0, 0, 0);
        __syncthreads();                        // reads done before restage
    }

    #pragma unroll
    for (int i = 0; i < 4; i++)
        #pragma unroll
        for (int j = 0; j < 4; j++)
            #pragma unroll
            for (int r = 0; r < 4; r++) {
                int rr = m0 + wr * 64 + i * 16 + g * 4 + r;   // C/D row = (l>>4)*4 + reg
                int cc = n0 + wc * 64 + j * 16 + c;           // C/D col = l&15
                if (OUT_BF16)
                    ((short*)Cv)[(size_t)rr * N + cc] = f2bf(acc[i][j][r]);
                else
                    ((float*)Cv)[(size_t)rr * N + cc] = acc[i][j][r];
            }
}

// Causal depthwise conv1d (K=3) + bias on bf16 qkv; splits -> Q (B,H,T,64,
// scaled QSCALE for exp2-domain softmax), K (B,T,64), V transposed (B,64,T).
__global__ __launch_bounds__(256) void conv_split(const short* __restrict__ qkv,
        const float* __restrict__ qw, const float* __restrict__ qb,
        const float* __restrict__ kw, const float* __restrict__ kbias,
        const float* __restrict__ vw, const float* __restrict__ vbias,
        short* __restrict__ Qs, short* __restrict__ Kb, short* __restrict__ Vt) {
    int idx = blockIdx.x * 256 + threadIdx.x;
    int ch = idx % O_;
    int bt = idx / O_;
    int t = bt % T_;
    int b = bt / T_;
    const short* p = qkv + (size_t)bt * O_ + ch;
    float x2 = bf2f(p[0]);
    float x1 = (t >= 1) ? bf2f(p[-O_]) : 0.f;
    float x0 = (t >= 2) ? bf2f(p[-2 * O_]) : 0.f;
    float w0, w1, w2, bias;
    if (ch < C_)             { w0 = qw[ch*3]; w1 = qw[ch*3+1]; w2 = qw[ch*3+2]; bias = qb[ch]; }
    else if (ch < C_ + HD_)  { int cc = ch - C_;       w0 = kw[cc*3]; w1 = kw[cc*3+1]; w2 = kw[cc*3+2]; bias = kbias[cc]; }
    else                     { int cc = ch - C_ - HD_; w0 = vw[cc*3]; w1 = vw[cc*3+1]; w2 = vw[cc*3+2]; bias = vbias[cc]; }
    float y = fmaf(x0, w0, fmaf(x1, w1, fmaf(x2, w2, bias)));
    if (ch < C_) {
        int h = ch >> 6, d = ch & 63;
        Qs[(((size_t)b * H_ + h) * T_ + t) * HD_ + d] = f2bf(y * QSCALE);
    } else if (ch < C_ + HD_) {
        Kb[((size_t)b * T_ + t) * HD_ + (ch - C_)] = f2bf(y);
    } else {
        Vt[((size_t)b * HD_ + (ch - C_ - HD_)) * T_ + t] = f2bf(y);
    }
}

// Flash-style causal MQA — EXACT round-12 kernel (best measured: 71.7 us).
// 4-wave sum-balanced blocks, swapped QK^T (32x32x16), exp2 softmax, tree
// reductions, defer-max (T13), permlane32_swap (T12), K-tile reg prefetch.
// C/D layout (m74-verified): col=lane&31, row=(reg&3)+8*(reg>>2)+4*(lane>>5).
__global__ __launch_bounds__(256) void attn_kernel(const short* __restrict__ Qs,
        const short* __restrict__ Kb, const short* __restrict__ Vt,
        short* __restrict__ Y) {
    int bh = blockIdx.y;
    int b = bh >> 4;
    int h = bh & 15;
    int wid = threadIdx.x >> 6, l = threadIdx.x & 63;
    int ql = l & 31, hi = l >> 5;
    int k2 = blockIdx.x;                       // 0..15
    int qt = (wid < 2) ? (2 * k2 + wid) : (63 - 2 * k2 - (wid & 1));
    int qbase = qt * 32;
    int qi = qbase + ql;

    // Q B-fragments, 4 contraction steps of 16 over HD=64 (col=q=ql, d=hi*8+j)
    const short* Qp = Qs + ((size_t)bh * T_ + qi) * HD_ + hi * 8;
    bf16x8 qf[4];
    #pragma unroll
    for (int s = 0; s < 4; s++) qf[s] = *(const bf16x8*)(Qp + s * 16);

    f32x16 Oa0 = {}, Oa1 = {};                 // O^T, d-blocks [0,32) and [32,64)
    float mrow = -1e30f, lsum = 0.f;

    const short* Kbase = Kb + (size_t)b * T_ * HD_;
    const short* Vbase = Vt + (size_t)b * HD_ * T_;

    auto LDK = [&](int kt, bf16x8 (&dst)[8]) {
        #pragma unroll
        for (int s = 0; s < 4; s++) {
            dst[s]     = *(const bf16x8*)(Kbase + (size_t)(kt + ql) * HD_ + s * 16 + hi * 8);
            dst[4 + s] = *(const bf16x8*)(Kbase + (size_t)(kt + 32 + ql) * HD_ + s * 16 + hi * 8);
        }
    };

    int nt = (qt >> 1) + 1;
    bf16x8 ka[8], kb2[8];
    LDK(0, ka);
    for (int it = 0; it < nt; it++) {
        int kt0 = it * 64;
        // ---- S^T from prefetched K ----
        f32x16 sv0 = {}, sv1 = {};
        #pragma unroll
        for (int s = 0; s < 4; s++)
            sv0 = __builtin_amdgcn_mfma_f32_32x32x16_bf16(ka[s], qf[s], sv0, 0, 0, 0);
        #pragma unroll
        for (int s = 0; s < 4; s++)
            sv1 = __builtin_amdgcn_mfma_f32_32x32x16_bf16(ka[4 + s], qf[s], sv1, 0, 0, 0);
        // ---- issue next tile's K loads (fly during softmax + PV) ----
        int itn = (it + 1 < nt) ? (it + 1) : it;
        LDK(itn * 64, kb2);
        // ---- causal mask (last tile only; scale folded into Q) ----
        if (kt0 + 64 > qbase) {
            #pragma unroll
            for (int r = 0; r < 16; r++) {
                int kl = (r & 3) + 8 * (r >> 2) + 4 * hi;
                if (kt0 + kl > qi)      sv0[r] = -1e30f;
                if (kt0 + 32 + kl > qi) sv1[r] = -1e30f;
            }
        }
        // ---- row max: depth-5 tree + cross-half combine ----
        float t8[8];
        #pragma unroll
        for (int r = 0; r < 8; r++)
            t8[r] = fmaxf(fmaxf(sv0[r], sv0[r + 8]), fmaxf(sv1[r], sv1[r + 8]));
        float pmax = fmaxf(fmaxf(fmaxf(t8[0], t8[4]), fmaxf(t8[1], t8[5])),
                           fmaxf(fmaxf(t8[2], t8[6]), fmaxf(t8[3], t8[7])));
        pmax = xmax32(pmax);
        // ---- defer-max (T13): rescale only when max grew past THR=8 ----
        if (!__all(pmax <= mrow + 8.f)) {
            float nm = fmaxf(mrow, pmax);
            float alpha = exp2fast(mrow - nm);
            mrow = nm;
            lsum *= alpha;
            #pragma unroll
            for (int r = 0; r < 16; r++) { Oa0[r] *= alpha; Oa1[r] *= alpha; }
        }
        // ---- P = exp2(S - m); sum via depth-5 tree + cross-half add ----
        #pragma unroll
        for (int r = 0; r < 16; r++) sv0[r] = exp2fast(sv0[r] - mrow);
        #pragma unroll
        for (int r = 0; r < 16; r++) sv1[r] = exp2fast(sv1[r] - mrow);
        float s8[8];
        #pragma unroll
        for (int r = 0; r < 8; r++)
            s8[r] = (sv0[r] + sv0[r + 8]) + (sv1[r] + sv1[r + 8]);
        float psum = ((s8[0] + s8[4]) + (s8[1] + s8[5])) +
                     ((s8[2] + s8[6]) + (s8[3] + s8[7]));
        lsum += xadd32(psum);
        // ---- P redistribution: cvt_pk + permlane32_swap ----
        #pragma unroll
        for (int sub = 0; sub < 2; sub++) {
            #pragma unroll
            for (int hh = 0; hh < 2; hh++) {
                unsigned X0, X1, X2, X3;
                if (sub == 0) {
                    X0 = cvtpk(sv0[hh * 8 + 0], sv0[hh * 8 + 1]);
                    X1 = cvtpk(sv0[hh * 8 + 2], sv0[hh * 8 + 3]);
                    X2 = cvtpk(sv0[hh * 8 + 4], sv0[hh * 8 + 5]);
                    X3 = cvtpk(sv0[hh * 8 + 6], sv0[hh * 8 + 7]);
                } else {
                    X0 = cvtpk(sv1[hh * 8 + 0], sv1[hh * 8 + 1]);
                    X1 = cvtpk(sv1[hh * 8 + 2], sv1[hh * 8 + 3]);
                    X2 = cvtpk(sv1[hh * 8 + 4], sv1[hh * 8 + 5]);
                    X3 = cvtpk(sv1[hh * 8 + 6], sv1[hh * 8 + 7]);
                }
                u32x2 r02 = pswap(X0, X2);
                u32x2 r13 = pswap(X1, X3);
                union { u32x4 u; bf16x8 v; } pw;
                pw.u[0] = r02[0];   // k elems (hi*8 + 0,1)
                pw.u[1] = r13[0];   // k elems (hi*8 + 2,3)
                pw.u[2] = r02[1];   // k elems (hi*8 + 4,5)
                pw.u[3] = r13[1];   // k elems (hi*8 + 6,7)
                int koff = kt0 + sub * 32 + hh * 16 + hi * 8;
                bf16x8 va0 = *(const bf16x8*)(Vbase + (size_t)ql * T_ + koff);
                bf16x8 va1 = *(const bf16x8*)(Vbase + (size_t)(32 + ql) * T_ + koff);
                Oa0 = __builtin_amdgcn_mfma_f32_32x32x16_bf16(va0, pw.v, Oa0, 0, 0, 0);
                Oa1 = __builtin_amdgcn_mfma_f32_32x32x16_bf16(va1, pw.v, Oa1, 0, 0, 0);
            }
        }
        // ---- rotate prefetch buffer ----
        #pragma unroll
        for (int s = 0; s < 8; s++) ka[s] = kb2[s];
    }
    // ---- epilogue: normalize, write one Y-row segment per lane ----
    float inv = 1.f / lsum;
    size_t orow = ((size_t)b * T_ + qi) * C_ + h * HD_;
    #pragma unroll
    for (int r = 0; r < 16; r += 2) {
        int d = (r & 3) + 8 * (r >> 2) + 4 * hi;       // r even -> d even; (r,r+1)->(d,d+1)
        *(unsigned*)(Y + orow + d)      = cvtpk(Oa0[r] * inv, Oa0[r + 1] * inv);
        *(unsigned*)(Y + orow + 32 + d) = cvtpk(Oa1[r] * inv, Oa1[r + 1] * inv);
    }
}

extern "C" void kernel_launch(void* const* d_in, const int* in_sizes, int n_in,
                              void* d_out, int out_size, void* d_ws, size_t ws_size,
                              hipStream_t stream) {
    const float* x     = (const float*)d_in[0];
    const float* Wqkv  = (const float*)d_in[1];
    const float* qw    = (const float*)d_in[2];
    const float* qb    = (const float*)d_in[3];
    const float* kw    = (const float*)d_in[4];
    const float* kbias = (const float*)d_in[5];
    const float* vw    = (const float*)d_in[6];
    const float* vbias = (const float*)d_in[7];
    const float* Wproj = (const float*)d_in[8];

    char* ws = (char*)d_ws;
    short* xb     = (short*)ws;                    //  8388608 B (reused as Ybf later)
    short* Wqkvb  = (short*)(ws + 8388608);        //  2359296 B
    short* Wprojb = (short*)(ws + 10747904);       //  2097152 B
    short* qkvb   = (short*)(ws + 12845056);       //  9437184 B
    short* Qsc    = (short*)(ws + 22282240);       //  8388608 B
    short* Kbf    = (short*)(ws + 30670848);       //   524288 B
    short* Vtr    = (short*)(ws + 31195136);       //   524288 B  (total 31.7 MB)
    short* Ybf    = xb;                            // x dead after gemm1

    const int M = B_ * T_;  // 4096

    // 0) f32 -> bf16: x, Wqkv, Wproj
    cvt_bf16<<<dim3(3136), 256, 0, stream>>>(x, Wqkv, Wproj, xb, Wqkvb, Wprojb);

    // 1) qkv = x @ Wqkv^T  (bf16 out)   grid 32*9 = 288 (%8==0)
    gemm_bt<true><<<dim3((M / 128) * (O_ / 128)), 256, 0, stream>>>(
        xb, Wqkvb, qkvb, M, O_, C_);

    // 2) causal dwconv + split + scale + V-transpose
    conv_split<<<dim3((B_ * T_ * O_) / 256), 256, 0, stream>>>(
        qkvb, qw, qb, kw, kbias, vw, vbias, Qsc, Kbf, Vtr);

    // 3) causal MQA attention -> y (B,T,C) bf16   (round-12 structure)
    attn_kernel<<<dim3(16, B_ * H_), 256, 0, stream>>>(Qsc, Kbf, Vtr, Ybf);

    // 4) out = y @ Wproj^T -> f32 d_out   grid 32*8 = 256 (%8==0)
    gemm_bt<false><<<dim3((M / 128) * (C_ / 128)), 256, 0, stream>>>(
        Ybf, Wprojb, (float*)d_out, M, C_, C_);
}

// Round 16
// 137.074 us; speedup vs baseline: 1.2932x; 1.0747x over previous
//
#include <hip/hip_runtime.h>
#include <hip/hip_bf16.h>

#define B_ 2
#define T_ 2048
#define C_ 1024
#define H_ 16
#define HD_ 64
#define O_ 1152   // C + 2*HD

#define NX  (B_ * T_ * C_)      // 4194304
#define NW1 (O_ * C_)           // 1179648
#define NW2 (C_ * C_)           // 1048576

// softmax runs in exp2 domain: Q pre-scale = (1/8) * log2(e)
#define QSCALE 0.1803368801111244f

typedef __attribute__((ext_vector_type(8))) short bf16x8;
typedef __attribute__((ext_vector_type(4))) float f32x4;
typedef __attribute__((ext_vector_type(16))) float f32x16;
typedef __attribute__((ext_vector_type(4))) unsigned u32x4;
typedef __attribute__((ext_vector_type(2))) unsigned u32x2;

__device__ inline short f2bf(float f) {
    union { float f; unsigned u; } v; v.f = f;
    unsigned r = v.u + 0x7FFFu + ((v.u >> 16) & 1u);
    return (short)(r >> 16);
}
__device__ inline float bf2f(short s) {
    union { unsigned u; float f; } v; v.u = ((unsigned)(unsigned short)s) << 16;
    return v.f;
}
// native 2^x (v_exp_f32)
__device__ inline float exp2fast(float x) { return __builtin_amdgcn_exp2f(x); }
// packed bf16(lo) | bf16(hi)<<16, RNE
__device__ inline unsigned cvtpk(float lo, float hi) {
    unsigned r;
    asm("v_cvt_pk_bf16_f32 %0, %1, %2" : "=v"(r) : "v"(lo), "v"(hi));
    return r;
}
// permlane32_swap via builtin (hazard-safe: compiler inserts the required
// VALU->permlane wait states; raw inline asm did not - round 10 failure).
__device__ inline u32x2 pswap(unsigned a, unsigned b) {
    return __builtin_amdgcn_permlane32_swap(a, b, false, false);
}
// cross-half (lane^32) max/add, direction-agnostic
__device__ inline float xmax32(float x) {
    u32x2 r = pswap(__float_as_uint(x), __float_as_uint(x));
    return fmaxf(__uint_as_float(r[0]), __uint_as_float(r[1]));
}
__device__ inline float xadd32(float x) {
    u32x2 r = pswap(__float_as_uint(x), __float_as_uint(x));
    return __uint_as_float(r[0]) + __uint_as_float(r[1]);
}

// async global -> LDS, 16 B per lane (wave-uniform LDS base + lane*16)
#define GLL16(gp, lp) __builtin_amdgcn_global_load_lds( \
    (const __attribute__((address_space(1))) unsigned int*)(gp), \
    (__attribute__((address_space(3))) unsigned int*)(lp), 16, 0, 0)

// -------- f32 -> bf16 pre-conversion of x, Wqkv, Wproj (one launch) --------
__global__ __launch_bounds__(256) void cvt_bf16(const float* __restrict__ x,
        const float* __restrict__ w1, const float* __restrict__ w2,
        short* __restrict__ xb, short* __restrict__ w1b, short* __restrict__ w2b) {
    size_t i = ((size_t)blockIdx.x * 256 + threadIdx.x) * 8;
    const float* src; short* dst; size_t off;
    if (i < (size_t)NX)              { src = x;  dst = xb;  off = i; }
    else if (i < (size_t)NX + NW1)   { src = w1; dst = w1b; off = i - NX; }
    else                             { src = w2; dst = w2b; off = i - NX - NW1; }
    f32x4 a = *(const f32x4*)(src + off);
    f32x4 b = *(const f32x4*)(src + off + 4);
    bf16x8 r;
    r[0] = f2bf(a[0]); r[1] = f2bf(a[1]); r[2] = f2bf(a[2]); r[3] = f2bf(a[3]);
    r[4] = f2bf(b[0]); r[5] = f2bf(b[1]); r[6] = f2bf(b[2]); r[7] = f2bf(b[3]);
    *(bf16x8*)(dst + off) = r;
}

// C(M,N) = A(M,K) * B(N,K)^T, bf16 inputs, fp32 accum.
// v9: 128x64 block tile (576/512 blocks -> 2.25/2.0 per CU vs v8's 1.1) +
// LDS DOUBLE-BUFFER, one barrier per k-step: stage(it+1) issues right after
// the barrier and flies under compute(it). The barrier's vmcnt(0) drain
// bounds pipeline depth at 1, so block co-residency provides the rest of
// the overlap (the v8 grid couldn't: 1 block/CU).
// 4 waves (2x2), each wave 64x32 = 4x2 frags of 16x16x32.
template <bool OUT_BF16>
__global__ __launch_bounds__(256) void gemm_bt(const short* __restrict__ A,
                                               const short* __restrict__ Bm,
                                               void* __restrict__ Cv,
                                               int M, int N, int K) {
    __shared__ short lA[2][128 * 32];   // 16 KB
    __shared__ short lB[2][64 * 32];    //  8 KB
    int ntn = N >> 6;
    int nwg = (M >> 7) * ntn;
    int cpx = nwg >> 3;                         // grids are %8 == 0
    int bid = (int)blockIdx.x;
    int swz = (bid % 8) * cpx + bid / 8;        // bijective XCD swizzle
    int m0 = (swz / ntn) << 7;
    int n0 = (swz % ntn) << 6;
    int t = threadIdx.x;
    int wid = t >> 6, l = t & 63;
    int wr = wid >> 1, wc = wid & 1;
    int c = l & 15, g = l >> 4;

    // staging: thread t covers LDS bytes [t*16, t*16+16) = row t/4, k-chunk t%4
    const short* gA0 = A + (size_t)(m0 + (t >> 2)) * K + (t & 3) * 8;
    const short* gA1 = gA0 + (size_t)64 * K;
    const short* gB0 = Bm + (size_t)(n0 + (t >> 2)) * K + (t & 3) * 8;

    int nstep = K >> 5;
    f32x4 acc[4][2] = {};
    int cur = 0;
    GLL16(gA0, &lA[0][t * 8]);
    GLL16(gA1, &lA[0][64 * 32 + t * 8]);
    GLL16(gB0, &lB[0][t * 8]);
    for (int it = 0; it < nstep; it++) {
        __syncthreads();                        // drains stage into lX[cur]
        if (it + 1 < nstep) {                   // stage next, overlapped
            int k = (it + 1) << 5;
            GLL16(gA0 + k, &lA[cur ^ 1][t * 8]);
            GLL16(gA1 + k, &lA[cur ^ 1][64 * 32 + t * 8]);
            GLL16(gB0 + k, &lB[cur ^ 1][t * 8]);
        }
        const short* lap = &lA[cur][(wr * 64 + c) * 32 + g * 8];
        const short* lbp = &lB[cur][(wc * 32 + c) * 32 + g * 8];
        bf16x8 a[4], b[2];
        #pragma unroll
        for (int i = 0; i < 4; i++) a[i] = *(const bf16x8*)(lap + i * 16 * 32);
        #pragma unroll
        for (int j = 0; j < 2; j++) b[j] = *(const bf16x8*)(lbp + j * 16 * 32);
        #pragma unroll
        for (int i = 0; i < 4; i++)
            #pragma unroll
            for (int j = 0; j < 2; j++)
                acc[i][j] = __builtin_amdgcn_mfma_f32_16x16x32_bf16(a[i], b[j], acc[i][j], 0, 0, 0);
        cur ^= 1;
    }

    #pragma unroll
    for (int i = 0; i < 4; i++)
        #pragma unroll
        for (int j = 0; j < 2; j++)
            #pragma unroll
            for (int r = 0; r < 4; r++) {
                int rr = m0 + wr * 64 + i * 16 + g * 4 + r;   // C/D row = (l>>4)*4 + reg
                int cc = n0 + wc * 32 + j * 16 + c;           // C/D col = l&15
                if (OUT_BF16)
                    ((short*)Cv)[(size_t)rr * N + cc] = f2bf(acc[i][j][r]);
                else
                    ((float*)Cv)[(size_t)rr * N + cc] = acc[i][j][r];
            }
}

// Causal depthwise conv1d (K=3) + bias on bf16 qkv; splits -> Q (B,H,T,64,
// scaled QSCALE for exp2-domain softmax), K (B,T,64), V transposed (B,64,T).
__global__ __launch_bounds__(256) void conv_split(const short* __restrict__ qkv,
        const float* __restrict__ qw, const float* __restrict__ qb,
        const float* __restrict__ kw, const float* __restrict__ kbias,
        const float* __restrict__ vw, const float* __restrict__ vbias,
        short* __restrict__ Qs, short* __restrict__ Kb, short* __restrict__ Vt) {
    int idx = blockIdx.x * 256 + threadIdx.x;
    int ch = idx % O_;
    int bt = idx / O_;
    int t = bt % T_;
    int b = bt / T_;
    const short* p = qkv + (size_t)bt * O_ + ch;
    float x2 = bf2f(p[0]);
    float x1 = (t >= 1) ? bf2f(p[-O_]) : 0.f;
    float x0 = (t >= 2) ? bf2f(p[-2 * O_]) : 0.f;
    float w0, w1, w2, bias;
    if (ch < C_)             { w0 = qw[ch*3]; w1 = qw[ch*3+1]; w2 = qw[ch*3+2]; bias = qb[ch]; }
    else if (ch < C_ + HD_)  { int cc = ch - C_;       w0 = kw[cc*3]; w1 = kw[cc*3+1]; w2 = kw[cc*3+2]; bias = kbias[cc]; }
    else                     { int cc = ch - C_ - HD_; w0 = vw[cc*3]; w1 = vw[cc*3+1]; w2 = vw[cc*3+2]; bias = vbias[cc]; }
    float y = fmaf(x0, w0, fmaf(x1, w1, fmaf(x2, w2, bias)));
    if (ch < C_) {
        int h = ch >> 6, d = ch & 63;
        Qs[(((size_t)b * H_ + h) * T_ + t) * HD_ + d] = f2bf(y * QSCALE);
    } else if (ch < C_ + HD_) {
        Kb[((size_t)b * T_ + t) * HD_ + (ch - C_)] = f2bf(y);
    } else {
        Vt[((size_t)b * HD_ + (ch - C_ - HD_)) * T_ + t] = f2bf(y);
    }
}

// Flash-style causal MQA, v10 = round-12 kernel + V-LOAD HOIST: all 8 V
// fragments of the CURRENT tile are loaded right after the QK MFMAs, so
// their ~200-cyc L2 latency flies under the softmax instead of stalling
// the PV loop. +32 VGPR, free (occupancy is grid-limited at 2 waves/SIMD).
// C/D layout (m74-verified): col=lane&31, row=(reg&3)+8*(reg>>2)+4*(lane>>5).
__global__ __launch_bounds__(256) void attn_kernel(const short* __restrict__ Qs,
        const short* __restrict__ Kb, const short* __restrict__ Vt,
        short* __restrict__ Y) {
    int bh = blockIdx.y;
    int b = bh >> 4;
    int h = bh & 15;
    int wid = threadIdx.x >> 6, l = threadIdx.x & 63;
    int ql = l & 31, hi = l >> 5;
    int k2 = blockIdx.x;                       // 0..15
    int qt = (wid < 2) ? (2 * k2 + wid) : (63 - 2 * k2 - (wid & 1));
    int qbase = qt * 32;
    int qi = qbase + ql;

    // Q B-fragments, 4 contraction steps of 16 over HD=64 (col=q=ql, d=hi*8+j)
    const short* Qp = Qs + ((size_t)bh * T_ + qi) * HD_ + hi * 8;
    bf16x8 qf[4];
    #pragma unroll
    for (int s = 0; s < 4; s++) qf[s] = *(const bf16x8*)(Qp + s * 16);

    f32x16 Oa0 = {}, Oa1 = {};                 // O^T, d-blocks [0,32) and [32,64)
    float mrow = -1e30f, lsum = 0.f;

    const short* Kbase = Kb + (size_t)b * T_ * HD_;
    const short* Vbase = Vt + (size_t)b * HD_ * T_;

    auto LDK = [&](int kt, bf16x8 (&dst)[8]) {
        #pragma unroll
        for (int s = 0; s < 4; s++) {
            dst[s]     = *(const bf16x8*)(Kbase + (size_t)(kt + ql) * HD_ + s * 16 + hi * 8);
            dst[4 + s] = *(const bf16x8*)(Kbase + (size_t)(kt + 32 + ql) * HD_ + s * 16 + hi * 8);
        }
    };

    int nt = (qt >> 1) + 1;
    bf16x8 ka[8], kb2[8];
    LDK(0, ka);
    for (int it = 0; it < nt; it++) {
        int kt0 = it * 64;
        // ---- S^T from prefetched K ----
        f32x16 sv0 = {}, sv1 = {};
        #pragma unroll
        for (int s = 0; s < 4; s++)
            sv0 = __builtin_amdgcn_mfma_f32_32x32x16_bf16(ka[s], qf[s], sv0, 0, 0, 0);
        #pragma unroll
        for (int s = 0; s < 4; s++)
            sv1 = __builtin_amdgcn_mfma_f32_32x32x16_bf16(ka[4 + s], qf[s], sv1, 0, 0, 0);
        // ---- issue next tile's K loads + THIS tile's V loads (fly during
        //      softmax; V was the one unprefetched stream -> PV stalled) ----
        int itn = (it + 1 < nt) ? (it + 1) : it;
        LDK(itn * 64, kb2);
        bf16x8 vv0[4], vv1[4];                  // u = sub*2+hh -> koff = u*16
        #pragma unroll
        for (int u = 0; u < 4; u++) {
            int koff = kt0 + u * 16 + hi * 8;
            vv0[u] = *(const bf16x8*)(Vbase + (size_t)ql * T_ + koff);
            vv1[u] = *(const bf16x8*)(Vbase + (size_t)(32 + ql) * T_ + koff);
        }
        // ---- causal mask (last tile only; scale folded into Q) ----
        if (kt0 + 64 > qbase) {
            #pragma unroll
            for (int r = 0; r < 16; r++) {
                int kl = (r & 3) + 8 * (r >> 2) + 4 * hi;
                if (kt0 + kl > qi)      sv0[r] = -1e30f;
                if (kt0 + 32 + kl > qi) sv1[r] = -1e30f;
            }
        }
        // ---- row max: depth-5 tree + cross-half combine ----
        float t8[8];
        #pragma unroll
        for (int r = 0; r < 8; r++)
            t8[r] = fmaxf(fmaxf(sv0[r], sv0[r + 8]), fmaxf(sv1[r], sv1[r + 8]));
        float pmax = fmaxf(fmaxf(fmaxf(t8[0], t8[4]), fmaxf(t8[1], t8[5])),
                           fmaxf(fmaxf(t8[2], t8[6]), fmaxf(t8[3], t8[7])));
        pmax = xmax32(pmax);
        // ---- defer-max (T13): rescale only when max grew past THR=8 ----
        if (!__all(pmax <= mrow + 8.f)) {
            float nm = fmaxf(mrow, pmax);
            float alpha = exp2fast(mrow - nm);
            mrow = nm;
            lsum *= alpha;
            #pragma unroll
            for (int r = 0; r < 16; r++) { Oa0[r] *= alpha; Oa1[r] *= alpha; }
        }
        // ---- P = exp2(S - m); sum via depth-5 tree + cross-half add ----
        #pragma unroll
        for (int r = 0; r < 16; r++) sv0[r] = exp2fast(sv0[r] - mrow);
        #pragma unroll
        for (int r = 0; r < 16; r++) sv1[r] = exp2fast(sv1[r] - mrow);
        float s8[8];
        #pragma unroll
        for (int r = 0; r < 8; r++)
            s8[r] = (sv0[r] + sv0[r + 8]) + (sv1[r] + sv1[r + 8]);
        float psum = ((s8[0] + s8[4]) + (s8[1] + s8[5])) +
                     ((s8[2] + s8[6]) + (s8[3] + s8[7]));
        lsum += xadd32(psum);
        // ---- P redistribution: cvt_pk + permlane32_swap; PV from vv ----
        #pragma unroll
        for (int sub = 0; sub < 2; sub++) {
            #pragma unroll
            for (int hh = 0; hh < 2; hh++) {
                unsigned X0, X1, X2, X3;
                if (sub == 0) {
                    X0 = cvtpk(sv0[hh * 8 + 0], sv0[hh * 8 + 1]);
                    X1 = cvtpk(sv0[hh * 8 + 2], sv0[hh * 8 + 3]);
                    X2 = cvtpk(sv0[hh * 8 + 4], sv0[hh * 8 + 5]);
                    X3 = cvtpk(sv0[hh * 8 + 6], sv0[hh * 8 + 7]);
                } else {
                    X0 = cvtpk(sv1[hh * 8 + 0], sv1[hh * 8 + 1]);
                    X1 = cvtpk(sv1[hh * 8 + 2], sv1[hh * 8 + 3]);
                    X2 = cvtpk(sv1[hh * 8 + 4], sv1[hh * 8 + 5]);
                    X3 = cvtpk(sv1[hh * 8 + 6], sv1[hh * 8 + 7]);
                }
                u32x2 r02 = pswap(X0, X2);
                u32x2 r13 = pswap(X1, X3);
                union { u32x4 u; bf16x8 v; } pw;
                pw.u[0] = r02[0];   // k elems (hi*8 + 0,1)
                pw.u[1] = r13[0];   // k elems (hi*8 + 2,3)
                pw.u[2] = r02[1];   // k elems (hi*8 + 4,5)
                pw.u[3] = r13[1];   // k elems (hi*8 + 6,7)
                int u = sub * 2 + hh;
                Oa0 = __builtin_amdgcn_mfma_f32_32x32x16_bf16(vv0[u], pw.v, Oa0, 0, 0, 0);
                Oa1 = __builtin_amdgcn_mfma_f32_32x32x16_bf16(vv1[u], pw.v, Oa1, 0, 0, 0);
            }
        }
        // ---- rotate prefetch buffer ----
        #pragma unroll
        for (int s = 0; s < 8; s++) ka[s] = kb2[s];
    }
    // ---- epilogue: normalize, write one Y-row segment per lane ----
    float inv = 1.f / lsum;
    size_t orow = ((size_t)b * T_ + qi) * C_ + h * HD_;
    #pragma unroll
    for (int r = 0; r < 16; r += 2) {
        int d = (r & 3) + 8 * (r >> 2) + 4 * hi;       // r even -> d even; (r,r+1)->(d,d+1)
        *(unsigned*)(Y + orow + d)      = cvtpk(Oa0[r] * inv, Oa0[r + 1] * inv);
        *(unsigned*)(Y + orow + 32 + d) = cvtpk(Oa1[r] * inv, Oa1[r + 1] * inv);
    }
}

extern "C" void kernel_launch(void* const* d_in, const int* in_sizes, int n_in,
                              void* d_out, int out_size, void* d_ws, size_t ws_size,
                              hipStream_t stream) {
    const float* x     = (const float*)d_in[0];
    const float* Wqkv  = (const float*)d_in[1];
    const float* qw    = (const float*)d_in[2];
    const float* qb    = (const float*)d_in[3];
    const float* kw    = (const float*)d_in[4];
    const float* kbias = (const float*)d_in[5];
    const float* vw    = (const float*)d_in[6];
    const float* vbias = (const float*)d_in[7];
    const float* Wproj = (const float*)d_in[8];

    char* ws = (char*)d_ws;
    short* xb     = (short*)ws;                    //  8388608 B (reused as Ybf later)
    short* Wqkvb  = (short*)(ws + 8388608);        //  2359296 B
    short* Wprojb = (short*)(ws + 10747904);       //  2097152 B
    short* qkvb   = (short*)(ws + 12845056);       //  9437184 B
    short* Qsc    = (short*)(ws + 22282240);       //  8388608 B
    short* Kbf    = (short*)(ws + 30670848);       //   524288 B
    short* Vtr    = (short*)(ws + 31195136);       //   524288 B  (total 31.7 MB)
    short* Ybf    = xb;                            // x dead after gemm1

    const int M = B_ * T_;  // 4096

    // 0) f32 -> bf16: x, Wqkv, Wproj
    cvt_bf16<<<dim3(3136), 256, 0, stream>>>(x, Wqkv, Wproj, xb, Wqkvb, Wprojb);

    // 1) qkv = x @ Wqkv^T  (bf16 out)   grid 32*18 = 576 (%8==0)
    gemm_bt<true><<<dim3((M / 128) * (O_ / 64)), 256, 0, stream>>>(
        xb, Wqkvb, qkvb, M, O_, C_);

    // 2) causal dwconv + split + scale + V-transpose
    conv_split<<<dim3((B_ * T_ * O_) / 256), 256, 0, stream>>>(
        qkvb, qw, qb, kw, kbias, vw, vbias, Qsc, Kbf, Vtr);

    // 3) causal MQA attention -> y (B,T,C) bf16   (r12 structure + V-hoist)
    attn_kernel<<<dim3(16, B_ * H_), 256, 0, stream>>>(Qsc, Kbf, Vtr, Ybf);

    // 4) out = y @ Wproj^T -> f32 d_out   grid 32*16 = 512 (%8==0)
    gemm_bt<false><<<dim3((M / 128) * (C_ / 64)), 256, 0, stream>>>(
        Ybf, Wprojb, (float*)d_out, M, C_, C_);
}